// Round 4
// baseline (6996.507 us; speedup 1.0000x reference)
//
#include <hip/hip_runtime.h>
#include <hip/hip_fp16.h>
#include <cstdint>
#include <cstddef>

// x[512,4096] fp32 ; gate/up codes [11008,4096] i32 ; down codes [4096,11008] i32
// absmax blocks of 64 along K ; out [512,4096] fp32
//
// R4: (1) raw `s_waitcnt lgkmcnt(0); s_barrier` instead of __syncthreads —
// global loads (codes, A-frags) stay in flight across the barrier since the
// only cross-wave data is the B-tile ds_writes (lgkm). (2) A operand kept in
// MFMA-fragment-packed global layout (packed by cast/swiglu kernels) so every
// A load is 64x16B contiguous from L2. (3) fused gate+up dispatch retained
// (R3 measured FETCH = 1.07x ideal).

using float4v = __attribute__((ext_vector_type(4))) float;
using half8   = __attribute__((ext_vector_type(8))) _Float16;

__constant__ float NF4TAB[16] = {
  -1.0f, -0.6961928009986877f, -0.5250730514526367f, -0.39491748809814453f,
  -0.28444138169288635f, -0.18477343022823334f, -0.09105003625154495f, 0.0f,
  0.07958029955625534f, 0.16093020141124725f, 0.24611230194568634f,
  0.33791524171829224f, 0.44070982933044434f, 0.5626170039176941f,
  0.7229568362236023f, 1.0f };

// barrier that does NOT drain vmcnt: only LDS ordering (ds_writes of B tile).
#define BARRIER() asm volatile("s_waitcnt lgkmcnt(0)\n\ts_barrier" ::: "memory")

// Packed A layout (M=512 rows fixed): element (m,k) lives at
//   (( (k>>5)*32 + (m>>4) )*64 + ((k>>3)&3)*16 + (m&15) )*8 + (k&7)
// so a wave's MFMA A-fragment (16 m-rows x 32 k) is one contiguous
// 64-lane x 16B load: base + lane*8 halfs.

// C[512 x N] = A_packed * dequant(codes[N x K])^T
// Block 256M x 64N, BK=64, 4 waves, wave tile 64x64 (4x4 MFMA 16x16x32 f16).
// ATOMIC=false: r2 selects gate/up matrix; C stored f16 in PACKED layout.
// ATOMIC=true : r2 = K-chunk (split-K); fp32 atomicAdd into row-major outF.
template <bool ATOMIC>
__global__ __launch_bounds__(256, 2) void gemm_nf4(
    const __half* __restrict__ Apk,
    const int* __restrict__ c0, const float* __restrict__ am0,
    const int* __restrict__ c1, const float* __restrict__ am1,
    __half* __restrict__ o0, __half* __restrict__ o1,
    float* __restrict__ outF,
    int N, int K, int Kc, int Ntiles)
{
  __shared__ __half    Bb[2][64 * 72];   // 18 KB double-buffered B tile (pad 72)
  __shared__ unsigned  ptab[256];        // packed f16 pair {tab[lo],tab[hi]}

  const int tid  = threadIdx.x;
  const int lane = tid & 63;
  const int wave = tid >> 6;

  {
    __half2 pr = __floats2half2_rn(NF4TAB[tid & 15], NF4TAB[tid >> 4]);
    ptab[tid] = *(const unsigned*)&pr;
  }

  const int bid = blockIdx.x;
  const int mt  = bid & 1;               // 2 M-tiles of 256 rows
  const int r   = bid >> 1;
  const int nt  = r % Ntiles;
  const int r2  = r / Ntiles;            // matrix select (gate/up) or K-chunk

  const int k0 = ATOMIC ? r2 * Kc : 0;
  const int nk = Kc >> 6;
  const int* codes  = (!ATOMIC && r2) ? c1 : c0;
  const float* amax = (!ATOMIC && r2) ? am1 : am0;
  __half* outH      = (!ATOMIC && r2) ? o1 : o0;

  const int row0 = mt * 256;
  const int col0 = nt * 64;
  const int Kb   = K >> 6;

  // code staging: thread -> (row bn = tid>>2, quarter bq = tid&3)
  const int bn = tid >> 2;
  const int bq = tid & 3;
  const int4* cSrc   = (const int4*)(codes + (size_t)(col0 + bn) * K + k0);
  const float* amSrc = amax + (size_t)(col0 + bn) * Kb + (k0 >> 6);

  // packed-A bases
  const int kb0 = k0 >> 5;
  const int mb0 = (row0 >> 4) + wave * 4;

  float4v acc[4][4];
  {
    float4v z = {0.f, 0.f, 0.f, 0.f};
    #pragma unroll
    for (int i = 0; i < 4; ++i)
      #pragma unroll
      for (int j = 0; j < 4; ++j) acc[i][j] = z;
  }

  int4  cr[2][4];
  float amr[2];
  half8 apf[2][4];

#define LOADC(S, KT)                                                            \
  { const int4* _p = cSrc + (KT) * 16;                                          \
    cr[S][0] = _p[bq];      cr[S][1] = _p[4 + bq];                              \
    cr[S][2] = _p[8 + bq];  cr[S][3] = _p[12 + bq];                             \
    amr[S] = amSrc[KT]; }

#define DEQB(BUFI, S)                                                           \
  { const __half _ah = __float2half(amr[S]);                                    \
    const __half2 _am2 = __half2{_ah, _ah};                                     \
    _Pragma("unroll")                                                           \
    for (int _i = 0; _i < 4; ++_i) {                                            \
      unsigned _w0 = ptab[cr[S][_i].x | (cr[S][_i].y << 4)];                    \
      unsigned _w1 = ptab[cr[S][_i].z | (cr[S][_i].w << 4)];                    \
      __half2 _p0 = __hmul2(*(const __half2*)&_w0, _am2);                       \
      __half2 _p1 = __hmul2(*(const __half2*)&_w1, _am2);                       \
      uint2 _wv; _wv.x = *(const unsigned*)&_p0; _wv.y = *(const unsigned*)&_p1;\
      *(uint2*)&Bb[BUFI][bn * 72 + _i * 16 + bq * 4] = _wv; } }

#define LOADA(DST, KT, KK)                                                      \
  { _Pragma("unroll")                                                           \
    for (int _i = 0; _i < 4; ++_i)                                              \
      DST[_i] = *(const half8*)(Apk +                                           \
        ((size_t)((kb0 + (KT) * 2 + (KK)) * 32 + mb0 + _i) * 64 + lane) * 8); }

  // ---- prologue: codes for t=0 (slot0), t=1 (slot1); slot = t&1
  LOADC(0, 0);
  if (nk > 1) LOADC(1, 1);
  BARRIER();                       // ptab visible
  DEQB(0, 0);
  if (nk > 2) LOADC(0, 2);         // t=2 -> slot0
  LOADA(apf[0], 0, 0);
  BARRIER();                       // Bb[0] visible; code loads stay in flight

  for (int kt = 0; kt < nk; ++kt) {
    const int S = kt & 1, np = S ^ 1;
    if (kt + 1 < nk) {
      DEQB(np, np);                            // codes t=kt+1 (slot np), aged 2
      if (kt + 3 < nk) LOADC(np, kt + 3);      // refill freed slot
      LOADA(apf[np], kt + 1, 0);               // next-iter A frags
    }
    half8 a1[4];
    LOADA(a1, kt, 1);                          // kk=1 frags (hidden under kk=0)
    half8 bf[4];
    #pragma unroll
    for (int j = 0; j < 4; ++j)
      bf[j] = *(const half8*)&Bb[S][(j * 16 + (lane & 15)) * 72 + ((lane >> 4) << 3)];
    #pragma unroll
    for (int i = 0; i < 4; ++i)
      #pragma unroll
      for (int j = 0; j < 4; ++j)
        acc[i][j] = __builtin_amdgcn_mfma_f32_16x16x32_f16(apf[S][i], bf[j], acc[i][j], 0, 0, 0);
    #pragma unroll
    for (int j = 0; j < 4; ++j)
      bf[j] = *(const half8*)&Bb[S][(j * 16 + (lane & 15)) * 72 + 32 + ((lane >> 4) << 3)];
    #pragma unroll
    for (int i = 0; i < 4; ++i)
      #pragma unroll
      for (int j = 0; j < 4; ++j)
        acc[i][j] = __builtin_amdgcn_mfma_f32_16x16x32_f16(a1[i], bf[j], acc[i][j], 0, 0, 0);
    BARRIER();                     // lgkm only — VMEM stays outstanding
  }

  // ---- epilogue. C/D map: col = lane&15 (n), row = (lane>>4)*4 + reg (m)
  if (ATOMIC) {
    const int ccol0 = col0 + (lane & 15);
    const int crow0 = row0 + wave * 64 + ((lane >> 4) << 2);
    #pragma unroll
    for (int i = 0; i < 4; ++i)
      #pragma unroll
      for (int j = 0; j < 4; ++j)
        #pragma unroll
        for (int rr = 0; rr < 4; ++rr) {
          const size_t idx = (size_t)(crow0 + i * 16 + rr) * N + (ccol0 + j * 16);
          atomicAdd(&outF[idx], acc[i][j][rr]);
        }
  } else {
    // store C (m = token row, n = this GEMM's output col = down's K) PACKED:
    //   ((kb*32+mb)*64 + ((n>>3)&3)*16 + (m&15))*8 + (n&7)
    const int jj    = lane & 7;
    const int lb    = (lane >> 3) & 1;
    const int rbase = (lane >> 4) << 2;
    const int kb_c  = col0 >> 5;
    #pragma unroll
    for (int i = 0; i < 4; ++i) {
      const int mb = (row0 >> 4) + wave * 4 + i;
      #pragma unroll
      for (int j = 0; j < 4; ++j) {
        const int kb = kb_c + (j >> 1);
        const int lp = ((j & 1) * 2 + lb) * 16 + rbase;
        #pragma unroll
        for (int rr = 0; rr < 4; ++rr) {
          const size_t a = ((size_t)(kb * 32 + mb) * 64 + (lp + rr)) * 8 + jj;
          outH[a] = __float2half(acc[i][j][rr]);
        }
      }
    }
  }
#undef LOADC
#undef DEQB
#undef LOADA
}

// x fp32 row-major [512][4096] -> packed f16 fragment layout.
__global__ void cast_pack_kernel(const float* __restrict__ x,
                                 __half* __restrict__ xp, int nGrp) {
  int pid = blockIdx.x * blockDim.x + threadIdx.x;   // one per 8 halfs
  if (pid >= nGrp) return;
  const int lane = pid & 63;
  const int grp  = pid >> 6;
  const int mb   = grp & 31;          // M=512 -> 32 m-tiles
  const int kb   = grp >> 5;
  const int m = mb * 16 + (lane & 15);
  const int k = kb * 32 + ((lane >> 4) << 3);
  const float4* src = (const float4*)(x + (size_t)m * 4096 + k);
  float4 v0 = src[0], v1 = src[1];
  __half2 h0 = __floats2half2_rn(v0.x, v0.y), h1 = __floats2half2_rn(v0.z, v0.w);
  __half2 h2 = __floats2half2_rn(v1.x, v1.y), h3 = __floats2half2_rn(v1.z, v1.w);
  uint4 o;
  o.x = *(const unsigned*)&h0; o.y = *(const unsigned*)&h1;
  o.z = *(const unsigned*)&h2; o.w = *(const unsigned*)&h3;
  ((uint4*)xp)[pid] = o;
}

// elementwise silu(g)*u — layout-agnostic (g,u share the packed layout).
__global__ void swiglu_kernel(const __half* __restrict__ g,
                              const __half* __restrict__ u,
                              __half* __restrict__ h, int n2) {
  int i = blockIdx.x * blockDim.x + threadIdx.x;
  if (i < n2) {
    float2 gf = __half22float2(((const __half2*)g)[i]);
    float2 uf = __half22float2(((const __half2*)u)[i]);
    float h0 = gf.x / (1.f + __expf(-gf.x)) * uf.x;
    float h1 = gf.y / (1.f + __expf(-gf.y)) * uf.y;
    ((__half2*)h)[i] = __floats2half2_rn(h0, h1);
  }
}

extern "C" void kernel_launch(void* const* d_in, const int* in_sizes, int n_in,
                              void* d_out, int out_size, void* d_ws, size_t ws_size,
                              hipStream_t stream)
{
  (void)in_sizes; (void)n_in; (void)ws_size;
  const float* x            = (const float*)d_in[0];
  const int*   gate_codes   = (const int*)d_in[1];
  const float* gate_absmax  = (const float*)d_in[2];
  const int*   up_codes     = (const int*)d_in[3];
  const float* up_absmax    = (const float*)d_in[4];
  const int*   down_codes   = (const int*)d_in[5];
  const float* down_absmax  = (const float*)d_in[6];
  float* out = (float*)d_out;

  // ws: xp 4MB | g 11.3MB | u 11.3MB   (h = silu(g)*u written in place over g)
  __half* xp = (__half*)d_ws;
  __half* g  = xp + (size_t)512 * 4096;
  __half* u  = g  + (size_t)512 * 11008;

  hipMemsetAsync(d_out, 0, (size_t)out_size * sizeof(float), stream);

  cast_pack_kernel<<<1024, 256, 0, stream>>>(x, xp, (512 * 4096) / 8);

  // fused gate+up: 2 Mtiles x 172 Ntiles x 2 mats = 688 blocks
  gemm_nf4<false><<<688, 256, 0, stream>>>(xp, gate_codes, gate_absmax,
                                           up_codes, up_absmax,
                                           g, u, nullptr,
                                           11008, 4096, 4096, 172);

  swiglu_kernel<<<11008, 256, 0, stream>>>(g, u, g, (512 * 11008) / 2);

  // down: out += h * Wd^T, split-K=4: 2 x 64 x 4 = 512 blocks
  gemm_nf4<true><<<512, 256, 0, stream>>>(g, down_codes, down_absmax,
                                          nullptr, nullptr, nullptr, nullptr,
                                          out, 4096, 11008, 2752, 64);
}

// Round 5
// 709.922 us; speedup vs baseline: 9.8553x; 9.8553x over previous
//
#include <hip/hip_runtime.h>
#include <hip/hip_fp16.h>
#include <cstdint>
#include <cstddef>

// x[512,4096] fp32 ; gate/up codes [11008,4096] i32 ; down codes [4096,11008] i32
// absmax blocks of 64 along K ; out [512,4096] fp32
//
// R5 = R4 structure (lgkm-only barrier so VMEM stays in flight across iters;
// A kept in MFMA-fragment-packed layout so A loads are 64x16B dense; fused
// gate+up dispatch) + R3's compile-time double-buffer indices (manual 2x
// unroll) — R4's runtime S index spilled cr/apf/amr to scratch (VGPR 96,
// WRITE_SIZE 492MB, 55x VALU work).

using float4v = __attribute__((ext_vector_type(4))) float;
using half8   = __attribute__((ext_vector_type(8))) _Float16;

__constant__ float NF4TAB[16] = {
  -1.0f, -0.6961928009986877f, -0.5250730514526367f, -0.39491748809814453f,
  -0.28444138169288635f, -0.18477343022823334f, -0.09105003625154495f, 0.0f,
  0.07958029955625534f, 0.16093020141124725f, 0.24611230194568634f,
  0.33791524171829224f, 0.44070982933044434f, 0.5626170039176941f,
  0.7229568362236023f, 1.0f };

// barrier that does NOT drain vmcnt: only LDS ordering (B-tile ds_writes).
// Safe because no global_load_lds is used and all cross-wave data is in LDS.
#define BARRIER() asm volatile("s_waitcnt lgkmcnt(0)\n\ts_barrier" ::: "memory")

// Packed A layout (M=512 fixed): element (m,k) at
//   (((k>>5)*32 + (m>>4))*64 + ((k>>3)&3)*16 + (m&15))*8 + (k&7)
// -> a wave's MFMA A-fragment (16 m x 32 k) is one 64-lane x 16B dense load.

// C[512 x N] = A_packed * dequant(codes[N x K])^T
// Block 256M x 64N, BK=64, 4 waves, wave tile 64x64 (4x4 MFMA 16x16x32 f16).
// ATOMIC=false: r2 selects gate/up matrix; C stored f16 PACKED.
// ATOMIC=true : r2 = K-chunk (split-K); fp32 atomicAdd into row-major outF.
template <bool ATOMIC>
__global__ __launch_bounds__(256, 2) void gemm_nf4(
    const __half* __restrict__ Apk,
    const int* __restrict__ c0, const float* __restrict__ am0,
    const int* __restrict__ c1, const float* __restrict__ am1,
    __half* __restrict__ o0, __half* __restrict__ o1,
    float* __restrict__ outF,
    int N, int K, int Kc, int Ntiles)
{
  __shared__ __half    Bb[2][64 * 72];   // 18 KB double-buffered B tile (pad 72)
  __shared__ unsigned  ptab[256];        // packed f16 pair {tab[lo],tab[hi]}

  const int tid  = threadIdx.x;
  const int lane = tid & 63;
  const int wave = tid >> 6;

  {
    __half2 pr = __floats2half2_rn(NF4TAB[tid & 15], NF4TAB[tid >> 4]);
    ptab[tid] = *(const unsigned*)&pr;
  }

  const int bid = blockIdx.x;
  const int mt  = bid & 1;               // 2 M-tiles of 256 rows
  const int r   = bid >> 1;
  const int nt  = r % Ntiles;
  const int r2  = r / Ntiles;            // matrix select (gate/up) or K-chunk

  const int k0 = ATOMIC ? r2 * Kc : 0;
  const int nk = Kc >> 6;
  const int* codes  = (!ATOMIC && r2) ? c1 : c0;
  const float* amax = (!ATOMIC && r2) ? am1 : am0;
  __half* outH      = (!ATOMIC && r2) ? o1 : o0;

  const int row0 = mt * 256;
  const int col0 = nt * 64;
  const int Kb   = K >> 6;

  // code staging: thread -> (row bn = tid>>2, quarter bq = tid&3)
  const int bn = tid >> 2;
  const int bq = tid & 3;
  const int4* cSrc   = (const int4*)(codes + (size_t)(col0 + bn) * K + k0);
  const float* amSrc = amax + (size_t)(col0 + bn) * Kb + (k0 >> 6);

  // packed-A bases
  const int kb0 = k0 >> 5;
  const int mb0 = (row0 >> 4) + wave * 4;

  float4v acc[4][4];
  {
    float4v z = {0.f, 0.f, 0.f, 0.f};
    #pragma unroll
    for (int i = 0; i < 4; ++i)
      #pragma unroll
      for (int j = 0; j < 4; ++j) acc[i][j] = z;
  }

  int4  cr[2][4];      // all indices below are compile-time literals
  float amr[2];
  half8 apf[2][4];

#define LOADC(S, KT)                                                            \
  { const int4* _p = cSrc + (KT) * 16;                                          \
    cr[S][0] = _p[bq];      cr[S][1] = _p[4 + bq];                              \
    cr[S][2] = _p[8 + bq];  cr[S][3] = _p[12 + bq];                             \
    amr[S] = amSrc[KT]; }

#define DEQB(BUFI, S)                                                           \
  { const __half _ah = __float2half(amr[S]);                                    \
    const __half2 _am2 = __half2{_ah, _ah};                                     \
    _Pragma("unroll")                                                           \
    for (int _i = 0; _i < 4; ++_i) {                                            \
      unsigned _w0 = ptab[cr[S][_i].x | (cr[S][_i].y << 4)];                    \
      unsigned _w1 = ptab[cr[S][_i].z | (cr[S][_i].w << 4)];                    \
      __half2 _p0 = __hmul2(*(const __half2*)&_w0, _am2);                       \
      __half2 _p1 = __hmul2(*(const __half2*)&_w1, _am2);                       \
      uint2 _wv; _wv.x = *(const unsigned*)&_p0; _wv.y = *(const unsigned*)&_p1;\
      *(uint2*)&Bb[BUFI][bn * 72 + _i * 16 + bq * 4] = _wv; } }

#define LOADA(DST, KT, KK)                                                      \
  { _Pragma("unroll")                                                           \
    for (int _i = 0; _i < 4; ++_i)                                              \
      DST[_i] = *(const half8*)(Apk +                                           \
        ((size_t)((kb0 + (KT) * 2 + (KK)) * 32 + mb0 + _i) * 64 + lane) * 8); }

  // ---- prologue: codes for t=0 -> slot0, t=1 -> slot1 (slot = t&1)
  LOADC(0, 0);
  if (nk > 1) LOADC(1, 1);
  BARRIER();                       // ptab visible
  DEQB(0, 0);
  if (nk > 2) LOADC(0, 2);         // t=2 -> slot0
  LOADA(apf[0], 0, 0);
  BARRIER();                       // Bb[0] visible; code loads stay in flight

// S and NP are LITERAL 0/1 — keeps cr/apf/amr register-resident.
#define BODY(KT, S, NP)                                                         \
  { if ((KT) + 1 < nk) {                                                        \
      DEQB(NP, NP);                            /* codes t=KT+1, aged ~2 iters */\
      if ((KT) + 3 < nk) LOADC(NP, (KT) + 3);  /* refill freed slot */          \
      LOADA(apf[NP], (KT) + 1, 0);             /* next-iter A frags */          \
    }                                                                           \
    half8 a1[4];                                                                \
    LOADA(a1, KT, 1);                          /* kk=1 frags */                 \
    half8 bf[4];                                                                \
    _Pragma("unroll")                                                           \
    for (int _j = 0; _j < 4; ++_j)                                              \
      bf[_j] = *(const half8*)&Bb[S][(_j * 16 + (lane & 15)) * 72 + ((lane >> 4) << 3)]; \
    _Pragma("unroll")                                                           \
    for (int _i = 0; _i < 4; ++_i)                                              \
      _Pragma("unroll")                                                         \
      for (int _j = 0; _j < 4; ++_j)                                            \
        acc[_i][_j] = __builtin_amdgcn_mfma_f32_16x16x32_f16(apf[S][_i], bf[_j], acc[_i][_j], 0, 0, 0); \
    _Pragma("unroll")                                                           \
    for (int _j = 0; _j < 4; ++_j)                                              \
      bf[_j] = *(const half8*)&Bb[S][(_j * 16 + (lane & 15)) * 72 + 32 + ((lane >> 4) << 3)]; \
    _Pragma("unroll")                                                           \
    for (int _i = 0; _i < 4; ++_i)                                              \
      _Pragma("unroll")                                                         \
      for (int _j = 0; _j < 4; ++_j)                                            \
        acc[_i][_j] = __builtin_amdgcn_mfma_f32_16x16x32_f16(a1[_i], bf[_j], acc[_i][_j], 0, 0, 0); \
    BARRIER(); }                               /* lgkm only — VMEM in flight */

  int kt = 0;
  while (kt + 2 <= nk) { BODY(kt, 0, 1); BODY(kt + 1, 1, 0); kt += 2; }
  if (kt < nk) BODY(kt, 0, 1);     // odd-nk tail (down: nk=43; 42&1==0 ✓)

  // ---- epilogue. C/D map: col = lane&15 (n), row = (lane>>4)*4 + reg (m)
  if (ATOMIC) {
    const int ccol0 = col0 + (lane & 15);
    const int crow0 = row0 + wave * 64 + ((lane >> 4) << 2);
    #pragma unroll
    for (int i = 0; i < 4; ++i)
      #pragma unroll
      for (int j = 0; j < 4; ++j)
        #pragma unroll
        for (int rr = 0; rr < 4; ++rr) {
          const size_t idx = (size_t)(crow0 + i * 16 + rr) * N + (ccol0 + j * 16);
          atomicAdd(&outF[idx], acc[i][j][rr]);
        }
  } else {
    // store C packed (m = token row, n = this GEMM's out col = down's K):
    //   (((n>>5)*32 + (m>>4))*64 + ((n>>3)&3)*16 + (m&15))*8 + (n&7)
    // Block region is dense 64 KB -> L2 merges the 2B stores (R3-verified).
    const int jj    = lane & 7;
    const int lb    = (lane >> 3) & 1;
    const int rbase = (lane >> 4) << 2;
    const int kb_c  = col0 >> 5;
    #pragma unroll
    for (int i = 0; i < 4; ++i) {
      const int mb = (row0 >> 4) + wave * 4 + i;
      #pragma unroll
      for (int j = 0; j < 4; ++j) {
        const int kb = kb_c + (j >> 1);
        const int lp = ((j & 1) * 2 + lb) * 16 + rbase;
        #pragma unroll
        for (int rr = 0; rr < 4; ++rr) {
          const size_t a = ((size_t)(kb * 32 + mb) * 64 + (lp + rr)) * 8 + jj;
          outH[a] = __float2half(acc[i][j][rr]);
        }
      }
    }
  }
#undef LOADC
#undef DEQB
#undef LOADA
#undef BODY
}

// x fp32 row-major [512][4096] -> packed f16 fragment layout.
__global__ void cast_pack_kernel(const float* __restrict__ x,
                                 __half* __restrict__ xp, int nGrp) {
  int pid = blockIdx.x * blockDim.x + threadIdx.x;   // one per 8 halfs
  if (pid >= nGrp) return;
  const int lane = pid & 63;
  const int grp  = pid >> 6;
  const int mb   = grp & 31;          // M=512 -> 32 m-tiles
  const int kb   = grp >> 5;
  const int m = mb * 16 + (lane & 15);
  const int k = kb * 32 + ((lane >> 4) << 3);
  const float4* src = (const float4*)(x + (size_t)m * 4096 + k);
  float4 v0 = src[0], v1 = src[1];
  __half2 h0 = __floats2half2_rn(v0.x, v0.y), h1 = __floats2half2_rn(v0.z, v0.w);
  __half2 h2 = __floats2half2_rn(v1.x, v1.y), h3 = __floats2half2_rn(v1.z, v1.w);
  uint4 o;
  o.x = *(const unsigned*)&h0; o.y = *(const unsigned*)&h1;
  o.z = *(const unsigned*)&h2; o.w = *(const unsigned*)&h3;
  ((uint4*)xp)[pid] = o;
}

// elementwise silu(g)*u — layout-agnostic (g,u share the packed layout).
__global__ void swiglu_kernel(const __half* __restrict__ g,
                              const __half* __restrict__ u,
                              __half* __restrict__ h, int n2) {
  int i = blockIdx.x * blockDim.x + threadIdx.x;
  if (i < n2) {
    float2 gf = __half22float2(((const __half2*)g)[i]);
    float2 uf = __half22float2(((const __half2*)u)[i]);
    float h0 = gf.x / (1.f + __expf(-gf.x)) * uf.x;
    float h1 = gf.y / (1.f + __expf(-gf.y)) * uf.y;
    ((__half2*)h)[i] = __floats2half2_rn(h0, h1);
  }
}

extern "C" void kernel_launch(void* const* d_in, const int* in_sizes, int n_in,
                              void* d_out, int out_size, void* d_ws, size_t ws_size,
                              hipStream_t stream)
{
  (void)in_sizes; (void)n_in; (void)ws_size;
  const float* x            = (const float*)d_in[0];
  const int*   gate_codes   = (const int*)d_in[1];
  const float* gate_absmax  = (const float*)d_in[2];
  const int*   up_codes     = (const int*)d_in[3];
  const float* up_absmax    = (const float*)d_in[4];
  const int*   down_codes   = (const int*)d_in[5];
  const float* down_absmax  = (const float*)d_in[6];
  float* out = (float*)d_out;

  // ws: xp 4MB | g 11.3MB | u 11.3MB   (h = silu(g)*u written in place over g)
  __half* xp = (__half*)d_ws;
  __half* g  = xp + (size_t)512 * 4096;
  __half* u  = g  + (size_t)512 * 11008;

  hipMemsetAsync(d_out, 0, (size_t)out_size * sizeof(float), stream);

  cast_pack_kernel<<<1024, 256, 0, stream>>>(x, xp, (512 * 4096) / 8);

  // fused gate+up: 2 Mtiles x 172 Ntiles x 2 mats = 688 blocks
  gemm_nf4<false><<<688, 256, 0, stream>>>(xp, gate_codes, gate_absmax,
                                           up_codes, up_absmax,
                                           g, u, nullptr,
                                           11008, 4096, 4096, 172);

  swiglu_kernel<<<11008, 256, 0, stream>>>(g, u, g, (512 * 11008) / 2);

  // down: out += h * Wd^T, split-K=4: 2 x 64 x 4 = 512 blocks
  gemm_nf4<true><<<512, 256, 0, stream>>>(g, down_codes, down_absmax,
                                          nullptr, nullptr, nullptr, nullptr,
                                          out, 4096, 11008, 2752, 64);
}

// Round 6
// 658.729 us; speedup vs baseline: 10.6212x; 1.0777x over previous
//
#include <hip/hip_runtime.h>
#include <hip/hip_fp16.h>
#include <cstdint>
#include <cstddef>

// x[512,4096] fp32 ; gate/up codes [11008,4096] i32 ; down codes [4096,11008] i32
// absmax blocks of 64 along K ; out [512,4096] fp32
//
// R6 = R5 + strict load-aging: ALL consumed VMEM (A frags, codes, absmax) is
// issued >=1 iter before use, and each iteration's HBM code loads are the
// NEWEST vmem in program order. vmcnt retires in-order, so the compiler's
// waitcnt before MFMA (waiting on iter-old A frags) leaves the fresh HBM
// loads in flight — no per-iter drain. R5's bug: a1 (kk=1 A frags) was
// issued after LOADC and consumed in-iteration -> implicit full drain.

using float4v = __attribute__((ext_vector_type(4))) float;
using half8   = __attribute__((ext_vector_type(8))) _Float16;

__constant__ float NF4TAB[16] = {
  -1.0f, -0.6961928009986877f, -0.5250730514526367f, -0.39491748809814453f,
  -0.28444138169288635f, -0.18477343022823334f, -0.09105003625154495f, 0.0f,
  0.07958029955625534f, 0.16093020141124725f, 0.24611230194568634f,
  0.33791524171829224f, 0.44070982933044434f, 0.5626170039176941f,
  0.7229568362236023f, 1.0f };

// barrier that does NOT drain vmcnt: only LDS ordering (B-tile ds_writes).
// Safe: no global_load_lds; all cross-wave data is via LDS.
#define BARRIER() asm volatile("s_waitcnt lgkmcnt(0)\n\ts_barrier" ::: "memory")

// Packed A layout (M=512 fixed): element (m,k) at
//   (((k>>5)*32 + (m>>4))*64 + ((k>>3)&3)*16 + (m&15))*8 + (k&7)
// -> a wave's MFMA A-fragment (16 m x 32 k) is one 64-lane x 16B dense load.

// C[512 x N] = A_packed * dequant(codes[N x K])^T
// Block 256M x 64N, BK=64, 4 waves, wave tile 64x64 (4x4 MFMA 16x16x32 f16).
// ATOMIC=false: r2 selects gate/up matrix; C stored f16 PACKED.
// ATOMIC=true : r2 = K-chunk (split-K); fp32 atomicAdd into row-major outF.
template <bool ATOMIC>
__global__ __launch_bounds__(256, 2) void gemm_nf4(
    const __half* __restrict__ Apk,
    const int* __restrict__ c0, const float* __restrict__ am0,
    const int* __restrict__ c1, const float* __restrict__ am1,
    __half* __restrict__ o0, __half* __restrict__ o1,
    float* __restrict__ outF,
    int N, int K, int Kc, int Ntiles)
{
  __shared__ __half    Bb[2][64 * 72];   // 18 KB double-buffered B tile (pad 72)
  __shared__ unsigned  ptab[256];        // packed f16 pair {tab[lo],tab[hi]}

  const int tid  = threadIdx.x;
  const int lane = tid & 63;
  const int wave = tid >> 6;

  {
    __half2 pr = __floats2half2_rn(NF4TAB[tid & 15], NF4TAB[tid >> 4]);
    ptab[tid] = *(const unsigned*)&pr;
  }

  const int bid = blockIdx.x;
  const int mt  = bid & 1;               // 2 M-tiles of 256 rows
  const int r   = bid >> 1;
  const int nt  = r % Ntiles;
  const int r2  = r / Ntiles;            // matrix select (gate/up) or K-chunk

  const int k0 = ATOMIC ? r2 * Kc : 0;
  const int nk = Kc >> 6;
  const int* codes  = (!ATOMIC && r2) ? c1 : c0;
  const float* amax = (!ATOMIC && r2) ? am1 : am0;
  __half* outH      = (!ATOMIC && r2) ? o1 : o0;

  const int row0 = mt * 256;
  const int col0 = nt * 64;
  const int Kb   = K >> 6;

  // code staging: thread -> (row bn = tid>>2, quarter bq = tid&3)
  const int bn = tid >> 2;
  const int bq = tid & 3;
  const int4* cSrc   = (const int4*)(codes + (size_t)(col0 + bn) * K + k0);
  const float* amSrc = amax + (size_t)(col0 + bn) * Kb + (k0 >> 6);

  // packed-A bases
  const int kb0 = k0 >> 5;
  const int mb0 = (row0 >> 4) + wave * 4;

  float4v acc[4][4];
  {
    float4v z = {0.f, 0.f, 0.f, 0.f};
    #pragma unroll
    for (int i = 0; i < 4; ++i)
      #pragma unroll
      for (int j = 0; j < 4; ++j) acc[i][j] = z;
  }

  int4  cr[2][4];      // compile-time slot indices everywhere (R4 lesson)
  float amr[2];
  half8 apf[2][8];     // BOTH kk halves, prefetched one iter ahead

#define LOADC(S, KT)                                                            \
  { const int4* _p = cSrc + (KT) * 16;                                          \
    cr[S][0] = _p[bq];      cr[S][1] = _p[4 + bq];                              \
    cr[S][2] = _p[8 + bq];  cr[S][3] = _p[12 + bq];                             \
    amr[S] = amSrc[KT]; }

#define DEQB(BUFI, S)                                                           \
  { const __half _ah = __float2half(amr[S]);                                    \
    const __half2 _am2 = __half2{_ah, _ah};                                     \
    _Pragma("unroll")                                                           \
    for (int _i = 0; _i < 4; ++_i) {                                            \
      unsigned _w0 = ptab[cr[S][_i].x | (cr[S][_i].y << 4)];                    \
      unsigned _w1 = ptab[cr[S][_i].z | (cr[S][_i].w << 4)];                    \
      __half2 _p0 = __hmul2(*(const __half2*)&_w0, _am2);                       \
      __half2 _p1 = __hmul2(*(const __half2*)&_w1, _am2);                       \
      uint2 _wv; _wv.x = *(const unsigned*)&_p0; _wv.y = *(const unsigned*)&_p1;\
      *(uint2*)&Bb[BUFI][bn * 72 + _i * 16 + bq * 4] = _wv; } }

// load all 8 A-fragments of k-tile KT (kk=0 -> [0..3], kk=1 -> [4..7])
#define LOADA8(DST, KT)                                                         \
  { _Pragma("unroll")                                                           \
    for (int _i = 0; _i < 4; ++_i)                                              \
      DST[_i] = *(const half8*)(Apk +                                           \
        ((size_t)((kb0 + (KT) * 2) * 32 + mb0 + _i) * 64 + lane) * 8);          \
    _Pragma("unroll")                                                           \
    for (int _i = 0; _i < 4; ++_i)                                              \
      DST[4 + _i] = *(const half8*)(Apk +                                       \
        ((size_t)((kb0 + (KT) * 2 + 1) * 32 + mb0 + _i) * 64 + lane) * 8); }

  // ---- prologue: codes t=0 -> slot0, t=1 -> slot1 (slot = t&1)
  LOADC(0, 0);
  if (nk > 1) LOADC(1, 1);
  BARRIER();                       // ptab visible
  DEQB(0, 0);
  LOADA8(apf[0], 0);
  if (nk > 2) LOADC(0, 2);         // t=2 -> slot0; HBM loads newest
  BARRIER();                       // Bb[0] visible; vmem stays in flight

// S/NP literal 0/1. Issue order: LDS writes -> L2 A-prefetch -> HBM codes
// (newest) -> ds_reads -> MFMA on iter-old apf[S] -> lgkm barrier.
#define BODY(KT, S, NP)                                                         \
  { if ((KT) + 1 < nk) {                                                        \
      DEQB(NP, NP);                            /* codes t=KT+1, aged ~2 iters */\
      LOADA8(apf[NP], (KT) + 1);               /* L2 A frags for next iter */   \
      if ((KT) + 3 < nk) LOADC(NP, (KT) + 3);  /* HBM codes LAST */             \
    }                                                                           \
    half8 bf[4];                                                                \
    _Pragma("unroll")                                                           \
    for (int _j = 0; _j < 4; ++_j)                                              \
      bf[_j] = *(const half8*)&Bb[S][(_j * 16 + (lane & 15)) * 72 + ((lane >> 4) << 3)]; \
    _Pragma("unroll")                                                           \
    for (int _i = 0; _i < 4; ++_i)                                              \
      _Pragma("unroll")                                                         \
      for (int _j = 0; _j < 4; ++_j)                                            \
        acc[_i][_j] = __builtin_amdgcn_mfma_f32_16x16x32_f16(apf[S][_i], bf[_j], acc[_i][_j], 0, 0, 0); \
    _Pragma("unroll")                                                           \
    for (int _j = 0; _j < 4; ++_j)                                              \
      bf[_j] = *(const half8*)&Bb[S][(_j * 16 + (lane & 15)) * 72 + 32 + ((lane >> 4) << 3)]; \
    _Pragma("unroll")                                                           \
    for (int _i = 0; _i < 4; ++_i)                                              \
      _Pragma("unroll")                                                         \
      for (int _j = 0; _j < 4; ++_j)                                            \
        acc[_i][_j] = __builtin_amdgcn_mfma_f32_16x16x32_f16(apf[S][4 + _i], bf[_j], acc[_i][_j], 0, 0, 0); \
    BARRIER(); }                               /* lgkm only — VMEM in flight */

  int kt = 0;
  while (kt + 2 <= nk) { BODY(kt, 0, 1); BODY(kt + 1, 1, 0); kt += 2; }
  if (kt < nk) BODY(kt, 0, 1);     // odd-nk tail (down: nk=43; 42&1==0 ✓)

  // ---- epilogue. C/D map: col = lane&15 (n), row = (lane>>4)*4 + reg (m)
  if (ATOMIC) {
    const int ccol0 = col0 + (lane & 15);
    const int crow0 = row0 + wave * 64 + ((lane >> 4) << 2);
    #pragma unroll
    for (int i = 0; i < 4; ++i)
      #pragma unroll
      for (int j = 0; j < 4; ++j)
        #pragma unroll
        for (int rr = 0; rr < 4; ++rr) {
          const size_t idx = (size_t)(crow0 + i * 16 + rr) * N + (ccol0 + j * 16);
          atomicAdd(&outF[idx], acc[i][j][rr]);
        }
  } else {
    // store C packed (m = token row, n = this GEMM's out col = down's K):
    //   (((n>>5)*32 + (m>>4))*64 + ((n>>3)&3)*16 + (m&15))*8 + (n&7)
    // Block region is dense 64 KB -> L2 merges the 2B stores (R3-verified).
    const int jj    = lane & 7;
    const int lb    = (lane >> 3) & 1;
    const int rbase = (lane >> 4) << 2;
    const int kb_c  = col0 >> 5;
    #pragma unroll
    for (int i = 0; i < 4; ++i) {
      const int mb = (row0 >> 4) + wave * 4 + i;
      #pragma unroll
      for (int j = 0; j < 4; ++j) {
        const int kb = kb_c + (j >> 1);
        const int lp = ((j & 1) * 2 + lb) * 16 + rbase;
        #pragma unroll
        for (int rr = 0; rr < 4; ++rr) {
          const size_t a = ((size_t)(kb * 32 + mb) * 64 + (lp + rr)) * 8 + jj;
          outH[a] = __float2half(acc[i][j][rr]);
        }
      }
    }
  }
#undef LOADC
#undef DEQB
#undef LOADA8
#undef BODY
}

// x fp32 row-major [512][4096] -> packed f16 fragment layout.
__global__ void cast_pack_kernel(const float* __restrict__ x,
                                 __half* __restrict__ xp, int nGrp) {
  int pid = blockIdx.x * blockDim.x + threadIdx.x;   // one per 8 halfs
  if (pid >= nGrp) return;
  const int lane = pid & 63;
  const int grp  = pid >> 6;
  const int mb   = grp & 31;          // M=512 -> 32 m-tiles
  const int kb   = grp >> 5;
  const int m = mb * 16 + (lane & 15);
  const int k = kb * 32 + ((lane >> 4) << 3);
  const float4* src = (const float4*)(x + (size_t)m * 4096 + k);
  float4 v0 = src[0], v1 = src[1];
  __half2 h0 = __floats2half2_rn(v0.x, v0.y), h1 = __floats2half2_rn(v0.z, v0.w);
  __half2 h2 = __floats2half2_rn(v1.x, v1.y), h3 = __floats2half2_rn(v1.z, v1.w);
  uint4 o;
  o.x = *(const unsigned*)&h0; o.y = *(const unsigned*)&h1;
  o.z = *(const unsigned*)&h2; o.w = *(const unsigned*)&h3;
  ((uint4*)xp)[pid] = o;
}

// elementwise silu(g)*u — layout-agnostic (g,u share the packed layout).
__global__ void swiglu_kernel(const __half* __restrict__ g,
                              const __half* __restrict__ u,
                              __half* __restrict__ h, int n2) {
  int i = blockIdx.x * blockDim.x + threadIdx.x;
  if (i < n2) {
    float2 gf = __half22float2(((const __half2*)g)[i]);
    float2 uf = __half22float2(((const __half2*)u)[i]);
    float h0 = gf.x / (1.f + __expf(-gf.x)) * uf.x;
    float h1 = gf.y / (1.f + __expf(-gf.y)) * uf.y;
    ((__half2*)h)[i] = __floats2half2_rn(h0, h1);
  }
}

extern "C" void kernel_launch(void* const* d_in, const int* in_sizes, int n_in,
                              void* d_out, int out_size, void* d_ws, size_t ws_size,
                              hipStream_t stream)
{
  (void)in_sizes; (void)n_in; (void)ws_size;
  const float* x            = (const float*)d_in[0];
  const int*   gate_codes   = (const int*)d_in[1];
  const float* gate_absmax  = (const float*)d_in[2];
  const int*   up_codes     = (const int*)d_in[3];
  const float* up_absmax    = (const float*)d_in[4];
  const int*   down_codes   = (const int*)d_in[5];
  const float* down_absmax  = (const float*)d_in[6];
  float* out = (float*)d_out;

  // ws: xp 4MB | g 11.3MB | u 11.3MB   (h = silu(g)*u written in place over g)
  __half* xp = (__half*)d_ws;
  __half* g  = xp + (size_t)512 * 4096;
  __half* u  = g  + (size_t)512 * 11008;

  hipMemsetAsync(d_out, 0, (size_t)out_size * sizeof(float), stream);

  cast_pack_kernel<<<1024, 256, 0, stream>>>(x, xp, (512 * 4096) / 8);

  // fused gate+up: 2 Mtiles x 172 Ntiles x 2 mats = 688 blocks
  gemm_nf4<false><<<688, 256, 0, stream>>>(xp, gate_codes, gate_absmax,
                                           up_codes, up_absmax,
                                           g, u, nullptr,
                                           11008, 4096, 4096, 172);

  swiglu_kernel<<<11008, 256, 0, stream>>>(g, u, g, (512 * 11008) / 2);

  // down: out += h * Wd^T, split-K=4: 2 x 64 x 4 = 512 blocks
  gemm_nf4<true><<<512, 256, 0, stream>>>(g, down_codes, down_absmax,
                                          nullptr, nullptr, nullptr, nullptr,
                                          out, 4096, 11008, 2752, 64);
}